// Round 1
// baseline (1673.162 us; speedup 1.0000x reference)
//
#include <hip/hip_runtime.h>

typedef unsigned short u16;
typedef __attribute__((ext_vector_type(8))) short s8v;
typedef __attribute__((ext_vector_type(4))) float f32x4;

__device__ __forceinline__ u16 f2bf(float f) {
  unsigned int u = __float_as_uint(f);
  u += ((u >> 16) & 1u) + 0x7FFFu;
  return (u16)(u >> 16);
}
__device__ __forceinline__ float bf2f(u16 h) {
  return __uint_as_float(((unsigned int)h) << 16);
}
__device__ __forceinline__ void gl_lds16(const void* g, void* l) {
  __builtin_amdgcn_global_load_lds(
      (__attribute__((address_space(1))) void*)g,
      (__attribute__((address_space(3))) void*)l, 16, 0, 0);
}
__device__ __forceinline__ f32x4 mfma16(s8v a, s8v b, f32x4 c) {
  return __builtin_amdgcn_mfma_f32_16x16x32_bf16(a, b, c, 0, 0, 0);
}

// ---------------- transpose + fp32->bf16 convert: out[c][r] = bf16(in[r][c])
__global__ void transpose_cvt(const float* __restrict__ in, u16* __restrict__ out,
                              int rows, int cols, int ldo) {
  __shared__ float tile[32][33];
  int c0 = blockIdx.x * 32, r0 = blockIdx.y * 32;
  int tx = threadIdx.x, ty = threadIdx.y;  // 32 x 8
#pragma unroll
  for (int i = 0; i < 4; i++)
    tile[ty + i * 8][tx] = in[(long)(r0 + ty + i * 8) * cols + c0 + tx];
  __syncthreads();
#pragma unroll
  for (int i = 0; i < 4; i++)
    out[(long)(c0 + ty + i * 8) * ldo + r0 + tx] = f2bf(tile[tx][ty + i * 8]);
}

// ---------------- fill aug K-rows [2048,2080) of a transposed weight (ld=2080)
__global__ void fill_aug_k(u16* __restrict__ wt, int N, const float* __restrict__ bq,
                           const float* __restrict__ bk, const float* __restrict__ bv) {
  long idx = (long)blockIdx.x * 256 + threadIdx.x;
  if (idx >= (long)N * 32) return;
  int n = (int)(idx >> 5), j = (int)(idx & 31);
  float v = 0.f;
  if (bq && j < 8 && n < 2048) v = bq[j * 2048 + n];
  else if (bk && j >= 8 && j < 16 && n >= 2048 && n < 2176) v = bk[(j - 8) * 128 + (n - 2048)];
  else if (bv && j >= 16 && j < 24 && n >= 2176 && n < 2304) v = bv[(j - 16) * 128 + (n - 2176)];
  wt[(long)n * 2080 + 2048 + j] = f2bf(v);
}

// ---------------- layernorm: x fp32 (4096x2048) -> xn_aug bf16 cols [0,2048)
__global__ __launch_bounds__(256) void layernorm_k(const float* __restrict__ x,
                                                   const float* __restrict__ gamma,
                                                   u16* __restrict__ xn) {
  const int row = blockIdx.x, tid = threadIdx.x;
  const float* xr = x + (long)row * 2048 + tid * 8;
  float4 v0 = *(const float4*)xr;
  float4 v1 = *(const float4*)(xr + 4);
  float vals[8] = {v0.x, v0.y, v0.z, v0.w, v1.x, v1.y, v1.z, v1.w};
  float s = 0.f, q = 0.f;
#pragma unroll
  for (int e = 0; e < 8; e++) { s += vals[e]; q += vals[e] * vals[e]; }
#pragma unroll
  for (int off = 32; off > 0; off >>= 1) {
    s += __shfl_down(s, off, 64);
    q += __shfl_down(q, off, 64);
  }
  __shared__ float red[8];
  const int w = tid >> 6, lane = tid & 63;
  if (lane == 0) { red[w] = s; red[4 + w] = q; }
  __syncthreads();
  if (tid == 0) {
    float S = red[0] + red[1] + red[2] + red[3];
    float Q = red[4] + red[5] + red[6] + red[7];
    float mu = S * (1.f / 2048.f);
    float var = Q * (1.f / 2048.f) - mu * mu;
    red[0] = mu; red[1] = rsqrtf(var + 1e-5f);
  }
  __syncthreads();
  float mu = red[0], rs = red[1];
  const float* g = gamma + tid * 8;
  u16 ov[8];
#pragma unroll
  for (int e = 0; e < 8; e++) ov[e] = f2bf((vals[e] - mu) * rs * g[e]);
  *(s8v*)(xn + (long)row * 2080 + tid * 8) = *(const s8v*)ov;
}

// ---------------- t_q|t_k|t_v = xn @ a_* -> bf16 into xn_aug cols [2048,2080)
__global__ __launch_bounds__(256) void lora_down_x(u16* __restrict__ xn_aug,
                                                   const float* __restrict__ aq,
                                                   const float* __restrict__ ak,
                                                   const float* __restrict__ av) {
  const int row = blockIdx.x, tid = threadIdx.x;
  s8v xv = *(const s8v*)(xn_aug + (long)row * 2080 + tid * 8);
  float acc[3][8];
#pragma unroll
  for (int m = 0; m < 3; m++)
#pragma unroll
    for (int j = 0; j < 8; j++) acc[m][j] = 0.f;
  const float* mats[3] = {aq, ak, av};
#pragma unroll
  for (int e = 0; e < 8; e++) {
    float xe = bf2f((u16)xv[e]);
    int k = tid * 8 + e;
#pragma unroll
    for (int m = 0; m < 3; m++) {
      const float4* ap = (const float4*)(mats[m] + (long)k * 8);
      float4 a0 = ap[0], a1 = ap[1];
      acc[m][0] += xe * a0.x; acc[m][1] += xe * a0.y;
      acc[m][2] += xe * a0.z; acc[m][3] += xe * a0.w;
      acc[m][4] += xe * a1.x; acc[m][5] += xe * a1.y;
      acc[m][6] += xe * a1.z; acc[m][7] += xe * a1.w;
    }
  }
#pragma unroll
  for (int m = 0; m < 3; m++)
#pragma unroll
    for (int j = 0; j < 8; j++)
#pragma unroll
      for (int off = 32; off > 0; off >>= 1)
        acc[m][j] += __shfl_down(acc[m][j], off, 64);
  __shared__ float red[4][24];
  const int w = tid >> 6, lane = tid & 63;
  if (lane == 0)
    for (int m = 0; m < 3; m++)
      for (int j = 0; j < 8; j++) red[w][m * 8 + j] = acc[m][j];
  __syncthreads();
  if (tid < 32) {
    float v = 0.f;
    if (tid < 24) v = red[0][tid] + red[1][tid] + red[2][tid] + red[3][tid];
    xn_aug[(long)row * 2080 + 2048 + tid] = f2bf(v);
  }
}

// ---------------- t_o = ctx @ a_o -> bf16 into ctx_aug cols [2048,2080)
__global__ __launch_bounds__(256) void lora_down_ctx(u16* __restrict__ ctx_aug,
                                                     const float* __restrict__ ao) {
  const int row = blockIdx.x, tid = threadIdx.x;
  s8v xv = *(const s8v*)(ctx_aug + (long)row * 2080 + tid * 8);
  float acc[8];
#pragma unroll
  for (int j = 0; j < 8; j++) acc[j] = 0.f;
#pragma unroll
  for (int e = 0; e < 8; e++) {
    float xe = bf2f((u16)xv[e]);
    int k = tid * 8 + e;
    const float4* ap = (const float4*)(ao + (long)k * 8);
    float4 a0 = ap[0], a1 = ap[1];
    acc[0] += xe * a0.x; acc[1] += xe * a0.y; acc[2] += xe * a0.z; acc[3] += xe * a0.w;
    acc[4] += xe * a1.x; acc[5] += xe * a1.y; acc[6] += xe * a1.z; acc[7] += xe * a1.w;
  }
#pragma unroll
  for (int j = 0; j < 8; j++)
#pragma unroll
    for (int off = 32; off > 0; off >>= 1)
      acc[j] += __shfl_down(acc[j], off, 64);
  __shared__ float red[4][8];
  const int w = tid >> 6, lane = tid & 63;
  if (lane == 0)
    for (int j = 0; j < 8; j++) red[w][j] = acc[j];
  __syncthreads();
  if (tid < 32) {
    float v = 0.f;
    if (tid < 8) v = red[0][tid] + red[1][tid] + red[2][tid] + red[3][tid];
    ctx_aug[(long)row * 2080 + 2048 + tid] = f2bf(v);
  }
}

// ---------------- RoPE (+ q scale) in-place on proj cols [0,2048) (q) and [2048,2176) (k)
__global__ void rope_k(u16* __restrict__ proj) {
  int idx = blockIdx.x * 256 + threadIdx.x;  // 4096*17*64
  int i = idx & 63;
  int u = (idx >> 6) % 17;
  int row = idx / (17 * 64);
  int n = row & 2047;
  float invf = __powf(10000.f, -(float)i * (1.f / 64.f));
  float ang = (float)n * invf;
  float cs = cosf(ang), sn = sinf(ang);
  int cb = (u < 16) ? u * 128 : 2048;
  u16* p = proj + (long)row * 18688 + cb + i;
  float t1 = bf2f(p[0]), t2 = bf2f(p[64]);
  float sc = (u < 16) ? 0.08838834764831845f : 1.f;  // 128^-0.5 on q only
  p[0]  = f2bf((t1 * cs - t2 * sn) * sc);
  p[64] = f2bf((t2 * cs + t1 * sn) * sc);
}

// ---------------- h = silu(gate)*x1, in-place into x1 region of proj
__global__ void silu_mul_k(u16* __restrict__ proj) {
  long idx = (long)blockIdx.x * 256 + threadIdx.x;  // 4096*1024
  int row = (int)(idx >> 10);
  int c8 = (int)(idx & 1023) * 8;
  u16* px = proj + (long)row * 18688 + 2304 + c8;
  const u16* pg = proj + (long)row * 18688 + 10496 + c8;
  s8v xv = *(const s8v*)px;
  s8v gv = *(const s8v*)pg;
  u16 ov[8];
#pragma unroll
  for (int e = 0; e < 8; e++) {
    float x1 = bf2f((u16)xv[e]);
    float g = bf2f((u16)gv[e]);
    ov[e] = f2bf(x1 * g / (1.f + __expf(-g)));
  }
  *(s8v*)px = *(const s8v*)ov;
}

// ---------------- GEMM: C(MxN) = A(MxK,row,bf16) @ Bt(NxK,row,bf16)^T
enum { STORE_BF16 = 0, STORE_F32 = 1, ADD_F32 = 2 };
template <int MODE>
__global__ __launch_bounds__(256, 2) void gemm_bt(const u16* __restrict__ A, int lda,
                                                  const u16* __restrict__ Bt, int ldb,
                                                  void* __restrict__ Cv, int ldc, int K) {
  __shared__ u16 As[128 * 32];
  __shared__ u16 Bs[128 * 32];
  const int tid = threadIdx.x;
  const int w = tid >> 6, lane = tid & 63, quad = lane >> 4, l15 = lane & 15;
  const int wm = (w >> 1) * 64, wn = (w & 1) * 64;
  const long m0 = (long)blockIdx.y * 128;
  const long n0 = (long)blockIdx.x * 128;

  const int srow = lane >> 2;          // 16 rows per 1KB chunk
  const int scol = (lane & 3) * 8;     // 4 x 8-elem segments per row
  const int cc0 = w * 2, cc1 = cc0 + 1;
  const u16* ga0 = A + (m0 + cc0 * 16 + srow) * lda + scol;
  const u16* ga1 = A + (m0 + cc1 * 16 + srow) * lda + scol;
  const u16* gb0 = Bt + (n0 + cc0 * 16 + srow) * ldb + scol;
  const u16* gb1 = Bt + (n0 + cc1 * 16 + srow) * ldb + scol;
  u16* la0 = As + cc0 * 512;
  u16* la1 = As + cc1 * 512;
  u16* lb0 = Bs + cc0 * 512;
  u16* lb1 = Bs + cc1 * 512;

  f32x4 acc[4][4];
#pragma unroll
  for (int i = 0; i < 4; i++)
#pragma unroll
    for (int j = 0; j < 4; j++) acc[i][j] = {0.f, 0.f, 0.f, 0.f};

  for (int k0 = 0; k0 < K; k0 += 32) {
    gl_lds16(ga0 + k0, la0);
    gl_lds16(ga1 + k0, la1);
    gl_lds16(gb0 + k0, lb0);
    gl_lds16(gb1 + k0, lb1);
    __syncthreads();
    s8v af[4], bf[4];
#pragma unroll
    for (int mi = 0; mi < 4; mi++)
      af[mi] = *(const s8v*)(As + (wm + mi * 16 + l15) * 32 + quad * 8);
#pragma unroll
    for (int ni = 0; ni < 4; ni++)
      bf[ni] = *(const s8v*)(Bs + (wn + ni * 16 + l15) * 32 + quad * 8);
#pragma unroll
    for (int mi = 0; mi < 4; mi++)
#pragma unroll
      for (int ni = 0; ni < 4; ni++)
        acc[mi][ni] = mfma16(af[mi], bf[ni], acc[mi][ni]);
    __syncthreads();
  }
#pragma unroll
  for (int mi = 0; mi < 4; mi++)
#pragma unroll
    for (int r = 0; r < 4; r++) {
      long row = m0 + wm + mi * 16 + quad * 4 + r;
#pragma unroll
      for (int ni = 0; ni < 4; ni++) {
        long col = n0 + wn + ni * 16 + l15;
        float v = acc[mi][ni][r];
        if (MODE == STORE_BF16) ((u16*)Cv)[row * ldc + col] = f2bf(v);
        else if (MODE == STORE_F32) ((float*)Cv)[row * ldc + col] = v;
        else ((float*)Cv)[row * ldc + col] += v;
      }
    }
}

// ---------------- causal flash attention (MQA), q/k/v read from proj, ctx bf16 out
__global__ __launch_bounds__(256) void flash_k(const u16* __restrict__ proj,
                                               u16* __restrict__ ctx) {
  __shared__ u16 Kt[32 * 128];
  __shared__ u16 Vt[32 * 128];
  __shared__ u16 Pw[4 * 16 * 32];
  const int qt = blockIdx.x, h = blockIdx.y, b = blockIdx.z;
  const int tid = threadIdx.x;
  const int w = tid >> 6, lane = tid & 63, quad = lane >> 4, l15 = lane & 15;
  const int qbase = qt * 64 + w * 16;

  s8v qf[4];
  {
    long rowQ = (long)b * 2048 + qbase + l15;
    const u16* qp = proj + rowQ * 18688 + h * 128 + quad * 8;
#pragma unroll
    for (int kk = 0; kk < 4; kk++) qf[kk] = *(const s8v*)(qp + kk * 32);
  }
  f32x4 o[8];
#pragma unroll
  for (int i = 0; i < 8; i++) o[i] = {0.f, 0.f, 0.f, 0.f};
  float m_i[4] = {-1e30f, -1e30f, -1e30f, -1e30f};
  float l_i[4] = {0.f, 0.f, 0.f, 0.f};

  const int cc0 = w * 2, cc1 = cc0 + 1;
  const int key0 = cc0 * 4 + (lane >> 4);
  const int key1 = cc1 * 4 + (lane >> 4);
  const int d8 = (lane & 15) * 8;

  const int nkb = 2 * qt + 2;
  for (int kb = 0; kb < nkb; kb++) {
    const int k0 = kb * 32;
    {
      long r0 = (long)b * 2048 + k0;
      gl_lds16(proj + (r0 + key0) * 18688 + 2048 + d8, Kt + cc0 * 512);
      gl_lds16(proj + (r0 + key1) * 18688 + 2048 + d8, Kt + cc1 * 512);
      gl_lds16(proj + (r0 + key0) * 18688 + 2176 + d8, Vt + cc0 * 512);
      gl_lds16(proj + (r0 + key1) * 18688 + 2176 + d8, Vt + cc1 * 512);
    }
    __syncthreads();
    if (k0 <= qbase + 15) {  // wave-uniform skip of fully-masked key blocks
      f32x4 s[2];
#pragma unroll
      for (int ni = 0; ni < 2; ni++) {
        f32x4 a = {0.f, 0.f, 0.f, 0.f};
#pragma unroll
        for (int kk = 0; kk < 4; kk++) {
          s8v kf = *(const s8v*)(Kt + (ni * 16 + l15) * 128 + kk * 32 + quad * 8);
          a = mfma16(qf[kk], kf, a);
        }
        s[ni] = a;
      }
#pragma unroll
      for (int ni = 0; ni < 2; ni++) {
        int kg = k0 + ni * 16 + l15;
#pragma unroll
        for (int r = 0; r < 4; r++)
          if (kg > qbase + quad * 4 + r) s[ni][r] = -1e30f;
      }
      float al[4];
#pragma unroll
      for (int r = 0; r < 4; r++) {
        float mx = fmaxf(s[0][r], s[1][r]);
#pragma unroll
        for (int off = 8; off > 0; off >>= 1)
          mx = fmaxf(mx, __shfl_xor(mx, off, 16));
        float mn = fmaxf(m_i[r], mx);
        al[r] = __expf(m_i[r] - mn);
        m_i[r] = mn;
      }
#pragma unroll
      for (int ni = 0; ni < 2; ni++)
#pragma unroll
        for (int r = 0; r < 4; r++) s[ni][r] = __expf(s[ni][r] - m_i[r]);
#pragma unroll
      for (int r = 0; r < 4; r++) {
        float rs = s[0][r] + s[1][r];
#pragma unroll
        for (int off = 8; off > 0; off >>= 1)
          rs += __shfl_xor(rs, off, 16);
        l_i[r] = l_i[r] * al[r] + rs;
      }
      // P (C-layout) -> LDS -> A-layout, per-wave region, no block barrier needed
#pragma unroll
      for (int ni = 0; ni < 2; ni++)
#pragma unroll
        for (int r = 0; r < 4; r++)
          Pw[w * 512 + (quad * 4 + r) * 32 + ni * 16 + l15] = f2bf(s[ni][r]);
      __asm__ volatile("s_waitcnt lgkmcnt(0)" ::: "memory");
#pragma unroll
      for (int nt = 0; nt < 8; nt++)
#pragma unroll
        for (int r = 0; r < 4; r++) o[nt][r] *= al[r];
      s8v pf = *(const s8v*)(Pw + w * 512 + l15 * 32 + quad * 8);
#pragma unroll
      for (int nt = 0; nt < 8; nt++) {
        s8v vf;
#pragma unroll
        for (int j = 0; j < 8; j++)
          vf[j] = (short)Vt[(quad * 8 + j) * 128 + nt * 16 + l15];
        o[nt] = mfma16(pf, vf, o[nt]);
      }
    }
    __syncthreads();
  }
  float inv[4];
#pragma unroll
  for (int r = 0; r < 4; r++) inv[r] = 1.f / l_i[r];
#pragma unroll
  for (int nt = 0; nt < 8; nt++)
#pragma unroll
    for (int r = 0; r < 4; r++) {
      long row = (long)b * 2048 + qbase + quad * 4 + r;
      ctx[row * 2080 + h * 128 + nt * 16 + l15] = f2bf(o[nt][r] * inv[r]);
    }
}

// ---------------- workspace layout (bytes)
#define OFF_WF   0L                       // 18688x2080 bf16 = 77,742,080
#define OFF_WO   77742080L                // 2048x2080 bf16  =  8,519,680
#define OFF_WFF  86261760L                // 2048x8192 bf16  = 33,554,432
#define OFF_XN   119816192L               // 4096x2080 bf16  = 17,039,360
#define OFF_PROJ 136855552L               // 4096x18688 bf16 = 153,092,096
#define OFF_CTX  289947648L               // 4096x2080 bf16  = 17,039,360
#define WS_NEED  306987008L

extern "C" void kernel_launch(void* const* d_in, const int* in_sizes, int n_in,
                              void* d_out, int out_size, void* d_ws, size_t ws_size,
                              hipStream_t stream) {
  const float* x       = (const float*)d_in[0];
  const float* gamma   = (const float*)d_in[1];
  const float* w_fused = (const float*)d_in[2];
  const float* w_attn  = (const float*)d_in[3];
  const float* w_ff    = (const float*)d_in[4];
  const float* a_q = (const float*)d_in[5];
  const float* b_q = (const float*)d_in[6];
  const float* a_k = (const float*)d_in[7];
  const float* b_k = (const float*)d_in[8];
  const float* a_v = (const float*)d_in[9];
  const float* b_v = (const float*)d_in[10];
  const float* a_o = (const float*)d_in[11];
  const float* b_o = (const float*)d_in[12];
  float* out = (float*)d_out;
  if (ws_size < (size_t)WS_NEED) return;

  char* ws = (char*)d_ws;
  u16* wf_t    = (u16*)(ws + OFF_WF);
  u16* wo_t    = (u16*)(ws + OFF_WO);
  u16* wff_t   = (u16*)(ws + OFF_WFF);
  u16* xn_aug  = (u16*)(ws + OFF_XN);
  u16* proj    = (u16*)(ws + OFF_PROJ);
  u16* ctx_aug = (u16*)(ws + OFF_CTX);

  dim3 tb(32, 8);
  transpose_cvt<<<dim3(18688 / 32, 2048 / 32), tb, 0, stream>>>(w_fused, wf_t, 2048, 18688, 2080);
  transpose_cvt<<<dim3(2048 / 32, 2048 / 32), tb, 0, stream>>>(w_attn, wo_t, 2048, 2048, 2080);
  transpose_cvt<<<dim3(2048 / 32, 8192 / 32), tb, 0, stream>>>(w_ff, wff_t, 8192, 2048, 8192);
  fill_aug_k<<<(18688 * 32 + 255) / 256, 256, 0, stream>>>(wf_t, 18688, b_q, b_k, b_v);
  fill_aug_k<<<(2048 * 32 + 255) / 256, 256, 0, stream>>>(wo_t, 2048, b_o, nullptr, nullptr);

  layernorm_k<<<4096, 256, 0, stream>>>(x, gamma, xn_aug);
  lora_down_x<<<4096, 256, 0, stream>>>(xn_aug, a_q, a_k, a_v);

  // proj = xn_aug @ wf_t^T  (q|k|v|x1|gate with QKV-LoRA folded into K-aug)
  gemm_bt<STORE_BF16><<<dim3(18688 / 128, 4096 / 128), 256, 0, stream>>>(
      xn_aug, 2080, wf_t, 2080, proj, 18688, 2080);

  rope_k<<<(4096 * 17 * 64) / 256, 256, 0, stream>>>(proj);
  silu_mul_k<<<(4096 * 1024) / 256, 256, 0, stream>>>(proj);

  flash_k<<<dim3(32, 16, 2), 256, 0, stream>>>(proj, ctx_aug);
  lora_down_ctx<<<4096, 256, 0, stream>>>(ctx_aug, a_o);

  // d_out = ctx_aug @ wo_t^T (o-LoRA folded), then += h @ wff_t^T
  gemm_bt<STORE_F32><<<dim3(2048 / 128, 4096 / 128), 256, 0, stream>>>(
      ctx_aug, 2080, wo_t, 2080, out, 2048, 2080);
  gemm_bt<ADD_F32><<<dim3(2048 / 128, 4096 / 128), 256, 0, stream>>>(
      proj + 2304, 18688, wff_t, 8192, out, 2048, 8192);
}

// Round 2
// 1450.109 us; speedup vs baseline: 1.1538x; 1.1538x over previous
//
#include <hip/hip_runtime.h>

typedef unsigned short u16;
typedef __attribute__((ext_vector_type(8))) short s8v;
typedef __attribute__((ext_vector_type(4))) float f32x4;

__device__ __forceinline__ u16 f2bf(float f) {
  unsigned int u = __float_as_uint(f);
  u += ((u >> 16) & 1u) + 0x7FFFu;
  return (u16)(u >> 16);
}
__device__ __forceinline__ float bf2f(u16 h) {
  return __uint_as_float(((unsigned int)h) << 16);
}
__device__ __forceinline__ void gl_lds16(const void* g, void* l) {
  __builtin_amdgcn_global_load_lds(
      (__attribute__((address_space(1))) void*)g,
      (__attribute__((address_space(3))) void*)l, 16, 0, 0);
}
__device__ __forceinline__ f32x4 mfma16(s8v a, s8v b, f32x4 c) {
  return __builtin_amdgcn_mfma_f32_16x16x32_bf16(a, b, c, 0, 0, 0);
}

// ---------------- transpose + fp32->bf16 convert: out[c][r] = bf16(in[r][c])
__global__ void transpose_cvt(const float* __restrict__ in, u16* __restrict__ out,
                              int rows, int cols, int ldo) {
  __shared__ float tile[32][33];
  int c0 = blockIdx.x * 32, r0 = blockIdx.y * 32;
  int tx = threadIdx.x, ty = threadIdx.y;  // 32 x 8
#pragma unroll
  for (int i = 0; i < 4; i++)
    tile[ty + i * 8][tx] = in[(long)(r0 + ty + i * 8) * cols + c0 + tx];
  __syncthreads();
#pragma unroll
  for (int i = 0; i < 4; i++)
    out[(long)(c0 + ty + i * 8) * ldo + r0 + tx] = f2bf(tile[tx][ty + i * 8]);
}

// ---------------- V transpose: v_t[b][d][n] = proj[b,n][2176+d] (bf16)
__global__ void vtrans(const u16* __restrict__ proj, u16* __restrict__ v_t) {
  __shared__ u16 tile[32][33];
  int n0 = blockIdx.x * 32, d0 = blockIdx.y * 32, b = blockIdx.z;
  int tx = threadIdx.x, ty = threadIdx.y;  // 32 x 8
#pragma unroll
  for (int i = 0; i < 4; i++)
    tile[ty + i * 8][tx] =
        proj[((long)b * 2048 + n0 + ty + i * 8) * 18688 + 2176 + d0 + tx];
  __syncthreads();
#pragma unroll
  for (int i = 0; i < 4; i++)
    v_t[((long)b * 128 + d0 + ty + i * 8) * 2048 + n0 + tx] = tile[tx][ty + i * 8];
}

// ---------------- fill aug K-rows [2048,2080) of a transposed weight (ld=2080)
__global__ void fill_aug_k(u16* __restrict__ wt, int N, const float* __restrict__ bq,
                           const float* __restrict__ bk, const float* __restrict__ bv) {
  long idx = (long)blockIdx.x * 256 + threadIdx.x;
  if (idx >= (long)N * 32) return;
  int n = (int)(idx >> 5), j = (int)(idx & 31);
  float v = 0.f;
  if (bq && j < 8 && n < 2048) v = bq[j * 2048 + n];
  else if (bk && j >= 8 && j < 16 && n >= 2048 && n < 2176) v = bk[(j - 8) * 128 + (n - 2048)];
  else if (bv && j >= 16 && j < 24 && n >= 2176 && n < 2304) v = bv[(j - 16) * 128 + (n - 2176)];
  wt[(long)n * 2080 + 2048 + j] = f2bf(v);
}

// ---------------- layernorm: x fp32 (4096x2048) -> xn_aug bf16 cols [0,2048)
__global__ __launch_bounds__(256) void layernorm_k(const float* __restrict__ x,
                                                   const float* __restrict__ gamma,
                                                   u16* __restrict__ xn) {
  const int row = blockIdx.x, tid = threadIdx.x;
  const float* xr = x + (long)row * 2048 + tid * 8;
  float4 v0 = *(const float4*)xr;
  float4 v1 = *(const float4*)(xr + 4);
  float vals[8] = {v0.x, v0.y, v0.z, v0.w, v1.x, v1.y, v1.z, v1.w};
  float s = 0.f, q = 0.f;
#pragma unroll
  for (int e = 0; e < 8; e++) { s += vals[e]; q += vals[e] * vals[e]; }
#pragma unroll
  for (int off = 32; off > 0; off >>= 1) {
    s += __shfl_down(s, off, 64);
    q += __shfl_down(q, off, 64);
  }
  __shared__ float red[8];
  const int w = tid >> 6, lane = tid & 63;
  if (lane == 0) { red[w] = s; red[4 + w] = q; }
  __syncthreads();
  if (tid == 0) {
    float S = red[0] + red[1] + red[2] + red[3];
    float Q = red[4] + red[5] + red[6] + red[7];
    float mu = S * (1.f / 2048.f);
    float var = Q * (1.f / 2048.f) - mu * mu;
    red[0] = mu; red[1] = rsqrtf(var + 1e-5f);
  }
  __syncthreads();
  float mu = red[0], rs = red[1];
  const float* g = gamma + tid * 8;
  u16 ov[8];
#pragma unroll
  for (int e = 0; e < 8; e++) ov[e] = f2bf((vals[e] - mu) * rs * g[e]);
  *(s8v*)(xn + (long)row * 2080 + tid * 8) = *(const s8v*)ov;
}

// ---------------- t_q|t_k|t_v = xn @ a_* -> bf16 into xn_aug cols [2048,2080)
__global__ __launch_bounds__(256) void lora_down_x(u16* __restrict__ xn_aug,
                                                   const float* __restrict__ aq,
                                                   const float* __restrict__ ak,
                                                   const float* __restrict__ av) {
  const int row = blockIdx.x, tid = threadIdx.x;
  s8v xv = *(const s8v*)(xn_aug + (long)row * 2080 + tid * 8);
  float acc[3][8];
#pragma unroll
  for (int m = 0; m < 3; m++)
#pragma unroll
    for (int j = 0; j < 8; j++) acc[m][j] = 0.f;
  const float* mats[3] = {aq, ak, av};
#pragma unroll
  for (int e = 0; e < 8; e++) {
    float xe = bf2f((u16)xv[e]);
    int k = tid * 8 + e;
#pragma unroll
    for (int m = 0; m < 3; m++) {
      const float4* ap = (const float4*)(mats[m] + (long)k * 8);
      float4 a0 = ap[0], a1 = ap[1];
      acc[m][0] += xe * a0.x; acc[m][1] += xe * a0.y;
      acc[m][2] += xe * a0.z; acc[m][3] += xe * a0.w;
      acc[m][4] += xe * a1.x; acc[m][5] += xe * a1.y;
      acc[m][6] += xe * a1.z; acc[m][7] += xe * a1.w;
    }
  }
#pragma unroll
  for (int m = 0; m < 3; m++)
#pragma unroll
    for (int j = 0; j < 8; j++)
#pragma unroll
      for (int off = 32; off > 0; off >>= 1)
        acc[m][j] += __shfl_down(acc[m][j], off, 64);
  __shared__ float red[4][24];
  const int w = tid >> 6, lane = tid & 63;
  if (lane == 0)
    for (int m = 0; m < 3; m++)
      for (int j = 0; j < 8; j++) red[w][m * 8 + j] = acc[m][j];
  __syncthreads();
  if (tid < 32) {
    float v = 0.f;
    if (tid < 24) v = red[0][tid] + red[1][tid] + red[2][tid] + red[3][tid];
    xn_aug[(long)row * 2080 + 2048 + tid] = f2bf(v);
  }
}

// ---------------- t_o = ctx @ a_o -> bf16 into ctx_aug cols [2048,2080)
__global__ __launch_bounds__(256) void lora_down_ctx(u16* __restrict__ ctx_aug,
                                                     const float* __restrict__ ao) {
  const int row = blockIdx.x, tid = threadIdx.x;
  s8v xv = *(const s8v*)(ctx_aug + (long)row * 2080 + tid * 8);
  float acc[8];
#pragma unroll
  for (int j = 0; j < 8; j++) acc[j] = 0.f;
#pragma unroll
  for (int e = 0; e < 8; e++) {
    float xe = bf2f((u16)xv[e]);
    int k = tid * 8 + e;
    const float4* ap = (const float4*)(ao + (long)k * 8);
    float4 a0 = ap[0], a1 = ap[1];
    acc[0] += xe * a0.x; acc[1] += xe * a0.y; acc[2] += xe * a0.z; acc[3] += xe * a0.w;
    acc[4] += xe * a1.x; acc[5] += xe * a1.y; acc[6] += xe * a1.z; acc[7] += xe * a1.w;
  }
#pragma unroll
  for (int j = 0; j < 8; j++)
#pragma unroll
    for (int off = 32; off > 0; off >>= 1)
      acc[j] += __shfl_down(acc[j], off, 64);
  __shared__ float red[4][8];
  const int w = tid >> 6, lane = tid & 63;
  if (lane == 0)
    for (int j = 0; j < 8; j++) red[w][j] = acc[j];
  __syncthreads();
  if (tid < 32) {
    float v = 0.f;
    if (tid < 8) v = red[0][tid] + red[1][tid] + red[2][tid] + red[3][tid];
    ctx_aug[(long)row * 2080 + 2048 + tid] = f2bf(v);
  }
}

// ---------------- RoPE (+ q scale) in-place on proj cols [0,2048) (q) and [2048,2176) (k)
__global__ void rope_k(u16* __restrict__ proj) {
  int idx = blockIdx.x * 256 + threadIdx.x;  // 4096*17*64
  int i = idx & 63;
  int u = (idx >> 6) % 17;
  int row = idx / (17 * 64);
  int n = row & 2047;
  float invf = __powf(10000.f, -(float)i * (1.f / 64.f));
  float ang = (float)n * invf;
  float cs = cosf(ang), sn = sinf(ang);
  int cb = (u < 16) ? u * 128 : 2048;
  u16* p = proj + (long)row * 18688 + cb + i;
  float t1 = bf2f(p[0]), t2 = bf2f(p[64]);
  float sc = (u < 16) ? 0.08838834764831845f : 1.f;  // 128^-0.5 on q only
  p[0]  = f2bf((t1 * cs - t2 * sn) * sc);
  p[64] = f2bf((t2 * cs + t1 * sn) * sc);
}

// ---------------- h = silu(gate)*x1, in-place into x1 region of proj
__global__ void silu_mul_k(u16* __restrict__ proj) {
  long idx = (long)blockIdx.x * 256 + threadIdx.x;  // 4096*1024
  int row = (int)(idx >> 10);
  int c8 = (int)(idx & 1023) * 8;
  u16* px = proj + (long)row * 18688 + 2304 + c8;
  const u16* pg = proj + (long)row * 18688 + 10496 + c8;
  s8v xv = *(const s8v*)px;
  s8v gv = *(const s8v*)pg;
  u16 ov[8];
#pragma unroll
  for (int e = 0; e < 8; e++) {
    float x1 = bf2f((u16)xv[e]);
    float g = bf2f((u16)gv[e]);
    ov[e] = f2bf(x1 * g / (1.f + __expf(-g)));
  }
  *(s8v*)px = *(const s8v*)ov;
}

// ---------------- GEMM: C(MxN) = A(MxK,row,bf16) @ Bt(NxK,row,bf16)^T
// grid: dim3(256, ceil(nbx/8)); 256 = 8 N-panels x 32 M-blocks (M fixed 4096).
// L2/L3 swizzle: within a dispatch panel all 32 M-blocks of 8 N-cols run
// together -> concurrent working set ~(17MB A + 8.5MB B) stays L3-resident.
enum { STORE_BF16 = 0, STORE_F32 = 1, ADD_F32 = 2 };
template <int MODE>
__global__ __launch_bounds__(256, 2) void gemm_bt(const u16* __restrict__ A, int lda,
                                                  const u16* __restrict__ Bt, int ldb,
                                                  void* __restrict__ Cv, int ldc, int K,
                                                  int nbx) {
  const int my = blockIdx.x & 31;
  const int mx = blockIdx.y * 8 + (blockIdx.x >> 5);
  if (mx >= nbx) return;
  __shared__ u16 As[128 * 32];
  __shared__ u16 Bs[128 * 32];
  const int tid = threadIdx.x;
  const int w = tid >> 6, lane = tid & 63, quad = lane >> 4, l15 = lane & 15;
  const int wm = (w >> 1) * 64, wn = (w & 1) * 64;
  const long m0 = (long)my * 128;
  const long n0 = (long)mx * 128;

  // staging: XOR bank swizzle — segment s of row r stored at s^((r>>1)&3).
  // lane's global segment = (lane&3) ^ ((lane>>3)&3); stays within same 64B.
  const int srow = lane >> 2;
  const int scol = (((lane & 3) ^ ((lane >> 3) & 3)) * 8);
  const int cc0 = w * 2, cc1 = cc0 + 1;
  const u16* ga0 = A + (m0 + cc0 * 16 + srow) * lda + scol;
  const u16* ga1 = A + (m0 + cc1 * 16 + srow) * lda + scol;
  const u16* gb0 = Bt + (n0 + cc0 * 16 + srow) * ldb + scol;
  const u16* gb1 = Bt + (n0 + cc1 * 16 + srow) * ldb + scol;
  u16* la0 = As + cc0 * 512;
  u16* la1 = As + cc1 * 512;
  u16* lb0 = Bs + cc0 * 512;
  u16* lb1 = Bs + cc1 * 512;

  // frag reads: physical segment = quad ^ ((l15>>1)&3)
  const int sseg = (quad ^ ((l15 >> 1) & 3)) * 8;

  f32x4 acc[4][4];
#pragma unroll
  for (int i = 0; i < 4; i++)
#pragma unroll
    for (int j = 0; j < 4; j++) acc[i][j] = {0.f, 0.f, 0.f, 0.f};

  for (int k0 = 0; k0 < K; k0 += 32) {
    gl_lds16(ga0 + k0, la0);
    gl_lds16(ga1 + k0, la1);
    gl_lds16(gb0 + k0, lb0);
    gl_lds16(gb1 + k0, lb1);
    __syncthreads();
    s8v af[4], bf[4];
#pragma unroll
    for (int mi = 0; mi < 4; mi++)
      af[mi] = *(const s8v*)(As + (wm + mi * 16 + l15) * 32 + sseg);
#pragma unroll
    for (int ni = 0; ni < 4; ni++)
      bf[ni] = *(const s8v*)(Bs + (wn + ni * 16 + l15) * 32 + sseg);
#pragma unroll
    for (int mi = 0; mi < 4; mi++)
#pragma unroll
      for (int ni = 0; ni < 4; ni++)
        acc[mi][ni] = mfma16(af[mi], bf[ni], acc[mi][ni]);
    __syncthreads();
  }
#pragma unroll
  for (int mi = 0; mi < 4; mi++)
#pragma unroll
    for (int r = 0; r < 4; r++) {
      long row = m0 + wm + mi * 16 + quad * 4 + r;
#pragma unroll
      for (int ni = 0; ni < 4; ni++) {
        long col = n0 + wn + ni * 16 + l15;
        float v = acc[mi][ni][r];
        if (MODE == STORE_BF16) ((u16*)Cv)[row * ldc + col] = f2bf(v);
        else if (MODE == STORE_F32) ((float*)Cv)[row * ldc + col] = v;
        else ((float*)Cv)[row * ldc + col] += v;
      }
    }
}

// ---------------- causal flash attention (MQA): K from proj, V from v_t (pre-transposed)
// LDS layouts (all XOR bank-swizzled, row stride 32 u16 = 64B):
//   Kt[4][32 keys][32 dims]  — chunk kk holds dims [kk*32, kk*32+32)
//   Vx[128 dims][32 keys]
//   Pw[wave][16 q][32 keys]
__global__ __launch_bounds__(256) void flash_k(const u16* __restrict__ proj,
                                               const u16* __restrict__ v_t,
                                               u16* __restrict__ ctx) {
  __shared__ u16 Kt[4 * 1024];
  __shared__ u16 Vx[8 * 512];
  __shared__ u16 Pw[4 * 512];
  const int qt = blockIdx.x, h = blockIdx.y, b = blockIdx.z;
  const int tid = threadIdx.x;
  const int w = tid >> 6, lane = tid & 63, quad = lane >> 4, l15 = lane & 15;
  const int qbase = qt * 64 + w * 16;

  s8v qf[4];
  {
    long rowQ = (long)b * 2048 + qbase + l15;
    const u16* qp = proj + rowQ * 18688 + h * 128 + quad * 8;
#pragma unroll
    for (int kk = 0; kk < 4; kk++) qf[kk] = *(const s8v*)(qp + kk * 32);
  }
  f32x4 o[8];
#pragma unroll
  for (int i = 0; i < 8; i++) o[i] = {0.f, 0.f, 0.f, 0.f};
  float m_i[4] = {-1e30f, -1e30f, -1e30f, -1e30f};
  float l_i[4] = {0.f, 0.f, 0.f, 0.f};

  // staging lane mapping (shared by K and V chunks)
  const int srow = lane >> 2;                              // row within 16-row chunk
  const int sseg = ((lane & 3) ^ ((lane >> 3) & 3)) * 8;   // swizzled 8-elem segment
  const int rseg = (quad ^ ((l15 >> 1) & 3)) * 8;          // frag-read physical segment

  const int nkb = 2 * qt + 2;
  for (int kb = 0; kb < nkb; kb++) {
    const int k0 = kb * 32;
    {
      // K: wave w stages dim-chunk kk=w, keys in two halves h2=0,1
      long rK = (long)b * 2048 + k0;
#pragma unroll
      for (int h2 = 0; h2 < 2; h2++)
        gl_lds16(proj + (rK + h2 * 16 + srow) * 18688 + 2048 + w * 32 + sseg,
                 Kt + w * 1024 + h2 * 512);
      // V: wave w stages dim-rows [w*32, w*32+32) from v_t
#pragma unroll
      for (int h2 = 0; h2 < 2; h2++)
        gl_lds16(v_t + ((long)b * 128 + w * 32 + h2 * 16 + srow) * 2048 + k0 + sseg,
                 Vx + (w * 2 + h2) * 512);
    }
    __syncthreads();
    if (k0 <= qbase + 15) {  // wave-uniform skip of fully-masked key blocks
      f32x4 s[2];
#pragma unroll
      for (int ni = 0; ni < 2; ni++) {
        f32x4 a = {0.f, 0.f, 0.f, 0.f};
#pragma unroll
        for (int kk = 0; kk < 4; kk++) {
          s8v kf = *(const s8v*)(Kt + kk * 1024 + (ni * 16 + l15) * 32 + rseg);
          a = mfma16(qf[kk], kf, a);
        }
        s[ni] = a;
      }
#pragma unroll
      for (int ni = 0; ni < 2; ni++) {
        int kg = k0 + ni * 16 + l15;
#pragma unroll
        for (int r = 0; r < 4; r++)
          if (kg > qbase + quad * 4 + r) s[ni][r] = -1e30f;
      }
      float al[4];
#pragma unroll
      for (int r = 0; r < 4; r++) {
        float mx = fmaxf(s[0][r], s[1][r]);
#pragma unroll
        for (int off = 8; off > 0; off >>= 1)
          mx = fmaxf(mx, __shfl_xor(mx, off, 16));
        float mn = fmaxf(m_i[r], mx);
        al[r] = __expf(m_i[r] - mn);
        m_i[r] = mn;
      }
#pragma unroll
      for (int ni = 0; ni < 2; ni++)
#pragma unroll
        for (int r = 0; r < 4; r++) s[ni][r] = __expf(s[ni][r] - m_i[r]);
#pragma unroll
      for (int r = 0; r < 4; r++) {
        float rs = s[0][r] + s[1][r];
#pragma unroll
        for (int off = 8; off > 0; off >>= 1)
          rs += __shfl_xor(rs, off, 16);
        l_i[r] = l_i[r] * al[r] + rs;
      }
      // P (C-layout) -> LDS (swizzled) -> A-layout, per-wave region
#pragma unroll
      for (int ni = 0; ni < 2; ni++)
#pragma unroll
        for (int r = 0; r < 4; r++) {
          int p = quad * 4 + r;
          int sg = ni * 2 + (l15 >> 3);
          int sp = sg ^ ((p >> 1) & 3);
          Pw[w * 512 + p * 32 + sp * 8 + (l15 & 7)] = f2bf(s[ni][r]);
        }
      __asm__ volatile("s_waitcnt lgkmcnt(0)" ::: "memory");
#pragma unroll
      for (int nt = 0; nt < 8; nt++)
#pragma unroll
        for (int r = 0; r < 4; r++) o[nt][r] *= al[r];
      s8v pf = *(const s8v*)(Pw + w * 512 + l15 * 32 + rseg);
#pragma unroll
      for (int nt = 0; nt < 8; nt++) {
        s8v vf = *(const s8v*)(Vx + (nt * 16 + l15) * 32 + rseg);
        o[nt] = mfma16(pf, vf, o[nt]);
      }
    }
    __syncthreads();
  }
  float inv[4];
#pragma unroll
  for (int r = 0; r < 4; r++) inv[r] = 1.f / l_i[r];
#pragma unroll
  for (int nt = 0; nt < 8; nt++)
#pragma unroll
    for (int r = 0; r < 4; r++) {
      long row = (long)b * 2048 + qbase + quad * 4 + r;
      ctx[row * 2080 + h * 128 + nt * 16 + l15] = f2bf(o[nt][r] * inv[r]);
    }
}

// ---------------- workspace layout (bytes)
#define OFF_WF   0L                       // 18688x2080 bf16 = 77,742,080
#define OFF_WO   77742080L                // 2048x2080 bf16  =  8,519,680
#define OFF_WFF  86261760L                // 2048x8192 bf16  = 33,554,432
#define OFF_XN   119816192L               // 4096x2080 bf16  = 17,039,360 (reused as v_t)
#define OFF_PROJ 136855552L               // 4096x18688 bf16 = 153,092,096
#define OFF_CTX  289947648L               // 4096x2080 bf16  = 17,039,360
#define WS_NEED  306987008L

extern "C" void kernel_launch(void* const* d_in, const int* in_sizes, int n_in,
                              void* d_out, int out_size, void* d_ws, size_t ws_size,
                              hipStream_t stream) {
  const float* x       = (const float*)d_in[0];
  const float* gamma   = (const float*)d_in[1];
  const float* w_fused = (const float*)d_in[2];
  const float* w_attn  = (const float*)d_in[3];
  const float* w_ff    = (const float*)d_in[4];
  const float* a_q = (const float*)d_in[5];
  const float* b_q = (const float*)d_in[6];
  const float* a_k = (const float*)d_in[7];
  const float* b_k = (const float*)d_in[8];
  const float* a_v = (const float*)d_in[9];
  const float* b_v = (const float*)d_in[10];
  const float* a_o = (const float*)d_in[11];
  const float* b_o = (const float*)d_in[12];
  float* out = (float*)d_out;
  if (ws_size < (size_t)WS_NEED) return;

  char* ws = (char*)d_ws;
  u16* wf_t    = (u16*)(ws + OFF_WF);
  u16* wo_t    = (u16*)(ws + OFF_WO);
  u16* wff_t   = (u16*)(ws + OFF_WFF);
  u16* xn_aug  = (u16*)(ws + OFF_XN);
  u16* v_t     = (u16*)(ws + OFF_XN);  // reuses xn_aug region after fused GEMM
  u16* proj    = (u16*)(ws + OFF_PROJ);
  u16* ctx_aug = (u16*)(ws + OFF_CTX);

  dim3 tb(32, 8);
  transpose_cvt<<<dim3(18688 / 32, 2048 / 32), tb, 0, stream>>>(w_fused, wf_t, 2048, 18688, 2080);
  transpose_cvt<<<dim3(2048 / 32, 2048 / 32), tb, 0, stream>>>(w_attn, wo_t, 2048, 2048, 2080);
  transpose_cvt<<<dim3(2048 / 32, 8192 / 32), tb, 0, stream>>>(w_ff, wff_t, 8192, 2048, 8192);
  fill_aug_k<<<(18688 * 32 + 255) / 256, 256, 0, stream>>>(wf_t, 18688, b_q, b_k, b_v);
  fill_aug_k<<<(2048 * 32 + 255) / 256, 256, 0, stream>>>(wo_t, 2048, b_o, nullptr, nullptr);

  layernorm_k<<<4096, 256, 0, stream>>>(x, gamma, xn_aug);
  lora_down_x<<<4096, 256, 0, stream>>>(xn_aug, a_q, a_k, a_v);

  // proj = xn_aug @ wf_t^T  (q|k|v|x1|gate with QKV-LoRA folded into K-aug)
  gemm_bt<STORE_BF16><<<dim3(256, (146 + 7) / 8), 256, 0, stream>>>(
      xn_aug, 2080, wf_t, 2080, proj, 18688, 2080, 146);

  rope_k<<<(4096 * 17 * 64) / 256, 256, 0, stream>>>(proj);
  silu_mul_k<<<(4096 * 1024) / 256, 256, 0, stream>>>(proj);
  vtrans<<<dim3(64, 4, 2), tb, 0, stream>>>(proj, v_t);

  flash_k<<<dim3(32, 16, 2), 256, 0, stream>>>(proj, v_t, ctx_aug);
  lora_down_ctx<<<4096, 256, 0, stream>>>(ctx_aug, a_o);

  // d_out = ctx_aug @ wo_t^T (o-LoRA folded), then += h @ wff_t^T
  gemm_bt<STORE_F32><<<dim3(256, 2), 256, 0, stream>>>(
      ctx_aug, 2080, wo_t, 2080, out, 2048, 2080, 16);
  gemm_bt<ADD_F32><<<dim3(256, 2), 256, 0, stream>>>(
      proj + 2304, 18688, wff_t, 8192, out, 2048, 8192, 16);
}